// Round 10
// baseline (210.109 us; speedup 1.0000x reference)
//
#include <hip/hip_runtime.h>

#define B_ 4
#define W_ 2048
#define C_ 1024
#define NH 16
#define KH 64

typedef __attribute__((ext_vector_type(8))) short short8;
typedef __attribute__((ext_vector_type(4))) short s16x4;
typedef __attribute__((ext_vector_type(4))) float f32x4;

__device__ __forceinline__ short f2bf(float f) {
    unsigned u = __builtin_bit_cast(unsigned, f);
    u = (u + 0x7FFFu + ((u >> 16) & 1u)) >> 16;
    return (short)u;
}
__device__ __forceinline__ float bf2f(short h) {
    return __builtin_bit_cast(float, ((unsigned)(unsigned short)h) << 16);
}

#define MFMA(a, b, cc) __builtin_amdgcn_mfma_f32_16x16x32_bf16(a, b, cc, 0, 0, 0)

// ---------------- k_prep: fused {cvt x, cvt Wp, Wf build, metric} ----------------
//   [0,1024)    : x fp32 -> bf16   (2048 float4/block, 8/thread)
//   [1024,1152) : Wp fp32 -> bf16  (2048 float4/block, 8/thread)
//   [1152,1408) : Wf[o][n*64+k] = sum_j T[n][k][j] * Wm[o][n*64+j]
//   [1408,1424) : metric[n] = P[n] @ P[n]^T  (fp32, consumed by fused GEMM1 epilogue)
__global__ __launch_bounds__(256) void k_prep(const float* __restrict__ x, const float* __restrict__ Wp,
                                              const float* __restrict__ Pm, const float* __restrict__ Tr,
                                              const float* __restrict__ Wm,
                                              short* __restrict__ x16, short* __restrict__ wp16,
                                              short* __restrict__ wf16, float* __restrict__ metric) {
    int bid = blockIdx.x, t = threadIdx.x;
    __shared__ float sA[KH * 65];
    __shared__ float sB[KH * KH];
    if (bid < 1152) {
        const float4* src;
        short4* dst;
        int base;
        if (bid < 1024) { src = (const float4*)x;  dst = (short4*)x16;  base = bid * 2048 + t; }
        else            { src = (const float4*)Wp; dst = (short4*)wp16; base = (bid - 1024) * 2048 + t; }
        float4 v[8];
        #pragma unroll
        for (int e = 0; e < 8; ++e) v[e] = src[base + e * 256];
        #pragma unroll
        for (int e = 0; e < 8; ++e) {
            short4 o;
            o.x = f2bf(v[e].x); o.y = f2bf(v[e].y); o.z = f2bf(v[e].z); o.w = f2bf(v[e].w);
            dst[base + e * 256] = o;
        }
    } else if (bid < 1408) {
        int idx = bid - 1152;
        int oseg = idx & 15, n = idx >> 4;
        for (int i = t; i < KH * KH; i += 256) {
            sA[(i & 63) * 65 + (i >> 6)] = Tr[n * KH * KH + i];   // T^T
            int r = i >> 6, c = i & 63;
            sB[i] = Wm[(oseg * KH + r) * C_ + n * KH + c];
        }
        __syncthreads();
        for (int e = t; e < KH * KH; e += 256) {
            int r = e >> 6, k = e & 63;
            float s = 0.f;
            #pragma unroll 8
            for (int j = 0; j < KH; ++j) s += sA[j * 65 + k] * sB[r * KH + j];
            wf16[(oseg * KH + r) * C_ + n * KH + k] = f2bf(s);
        }
    } else {
        int n = bid - 1408;
        const float* Pn = Pm + n * KH * KH;
        for (int i = t; i < KH * KH; i += 256) {
            float v = Pn[i];
            sB[i] = v;
            sA[(i & 63) * 65 + (i >> 6)] = v;                      // P^T
        }
        __syncthreads();
        float* Mn = metric + n * KH * KH;
        for (int e = t; e < KH * KH; e += 256) {
            int i = e >> 6, k = e & 63;
            float s = 0.f;
            #pragma unroll 8
            for (int j = 0; j < KH; ++j) s += sB[i * KH + j] * sA[j * 65 + k];
            Mn[e] = s;
        }
    }
}

// ---------------- 128x64-tile m97-style GEMM (+optional fused outer/qm epilogue) ----------------
// DO_OUTER (GEMM1 only): block (bm,bn) produces rows [bm*128,+128) x head bn = exactly two
// 64-row chunks of one head -> self-contained inputs for O_cc = P_cc^T P_cc (bf16 hi/lo into
// Chi/Clo) and qm = proj @ (M/8). Proj tile re-read from global after syncthreads (L2-hot,
// own-block writes). Pt reuses As LDS (4608 <= 8192 shorts); M/8 B-frags built in registers.
template <int OC, int STRIDE, bool OUT_FP32, bool DO_OUTER>
__global__ __launch_bounds__(256) void k_gemm(const short* __restrict__ A, const short* __restrict__ Bw,
                                              void* __restrict__ Out, const float* __restrict__ metric,
                                              short* __restrict__ Chi, short* __restrict__ Clo) {
    __shared__ short As[128 * 64];
    __shared__ short Bs[64 * 64];
    constexpr int NBX = OC / 64;
    int id = blockIdx.x + blockIdx.y * NBX;
    int fl = (id & 7) * (NBX * 64 / 8) + (id >> 3);   // bijective XCD swizzle (grid %8==0)
    int bm = fl / NBX, bn = fl % NBX;
    int t = threadIdx.x;
    int wave = t >> 6, lane = t & 63;
    int q = lane >> 4, c = lane & 15;
    int wy = wave >> 1, wx = wave & 1;                 // wave tile: 64 rows x 32 cols
    f32x4 acc[4][2] = {};
    int xsw = (c & 7);
    for (int k0 = 0; k0 < C_; k0 += 64) {
        __syncthreads();
        #pragma unroll
        for (int e = 0; e < 4; ++e) {
            int row = (e * 256 + t) >> 3;
            int ks = ((t & 7) ^ (row & 7)) * 8;
            __builtin_amdgcn_global_load_lds(
                (const __attribute__((address_space(1))) void*)&A[(size_t)(bm * 128 + row) * C_ + k0 + ks],
                (__attribute__((address_space(3))) void*)&As[e * 2048 + wave * 512], 16, 0, 0);
        }
        #pragma unroll
        for (int e = 0; e < 2; ++e) {
            int row = (e * 256 + t) >> 3;
            int ks = ((t & 7) ^ (row & 7)) * 8;
            __builtin_amdgcn_global_load_lds(
                (const __attribute__((address_space(1))) void*)&Bw[(size_t)(bn * 64 + row) * C_ + k0 + ks],
                (__attribute__((address_space(3))) void*)&Bs[e * 2048 + wave * 512], 16, 0, 0);
        }
        __syncthreads();
        #pragma unroll
        for (int kk = 0; kk < 64; kk += 32) {
            int o = kk >> 3;
            int xo = ((o + q) ^ xsw) * 8;
            short8 af[4], bfr[2];
            #pragma unroll
            for (int i = 0; i < 4; ++i)
                af[i] = *(const short8*)&As[(wy * 64 + i * 16 + c) * 64 + xo];
            #pragma unroll
            for (int j = 0; j < 2; ++j)
                bfr[j] = *(const short8*)&Bs[(wx * 32 + j * 16 + c) * 64 + xo];
            #pragma unroll
            for (int i = 0; i < 4; ++i)
                #pragma unroll
                for (int j = 0; j < 2; ++j)
                    acc[i][j] = MFMA(af[i], bfr[j], acc[i][j]);
        }
    }
    #pragma unroll
    for (int i = 0; i < 4; ++i)
        #pragma unroll
        for (int j = 0; j < 2; ++j)
            #pragma unroll
            for (int r = 0; r < 4; ++r) {
                int row = bm * 128 + wy * 64 + i * 16 + q * 4 + r;
                int col = bn * 64 + wx * 32 + j * 16 + c;
                if (OUT_FP32) ((float*)Out)[(size_t)row * STRIDE + col] = acc[i][j][r];
                else ((short*)Out)[(size_t)row * STRIDE + col] = f2bf(acc[i][j][r]);
            }

    if constexpr (DO_OUTER) {
        const short* pj = (const short*)Out;
        short* pjm = (short*)Out;
        short* Pt = As;                        // 64*72 = 4608 shorts, reuses staging LDS
        int n = bn;
        int Rbase = bm * 128;
        int b = Rbase >> 11;                   // / W_
        int ccA = (Rbase & (W_ - 1)) >> 6;     // even, in [0,30]
        size_t bnI = (size_t)(b * NH + n);
        // M/8 B-fragments in registers (rows ct*16+c of metric[n], fp32 -> bf16)
        const float* Mn = metric + n * 4096;
        short8 mb0[4], mb1[4];
        #pragma unroll
        for (int ct = 0; ct < 4; ++ct) {
            const float4* mrow = (const float4*)(Mn + (ct * 16 + c) * 64);
            float4 v0 = mrow[q * 2], v1 = mrow[q * 2 + 1];
            float4 v2 = mrow[8 + q * 2], v3 = mrow[8 + q * 2 + 1];
            short8 m0, m1;
            m0[0] = f2bf(v0.x * 0.125f); m0[1] = f2bf(v0.y * 0.125f);
            m0[2] = f2bf(v0.z * 0.125f); m0[3] = f2bf(v0.w * 0.125f);
            m0[4] = f2bf(v1.x * 0.125f); m0[5] = f2bf(v1.y * 0.125f);
            m0[6] = f2bf(v1.z * 0.125f); m0[7] = f2bf(v1.w * 0.125f);
            m1[0] = f2bf(v2.x * 0.125f); m1[1] = f2bf(v2.y * 0.125f);
            m1[2] = f2bf(v2.z * 0.125f); m1[3] = f2bf(v2.w * 0.125f);
            m1[4] = f2bf(v3.x * 0.125f); m1[5] = f2bf(v3.y * 0.125f);
            m1[6] = f2bf(v3.z * 0.125f); m1[7] = f2bf(v3.w * 0.125f);
            mb0[ct] = m0; mb1[ct] = m1;
        }
        __syncthreads();                       // proj stores drained; As free
        // ---- stage Pt for chunk 0 ----
        #pragma unroll
        for (int e = 0; e < 2; ++e) {
            int chv = e * 256 + t, row = chv >> 3, sub = chv & 7;
            short8 p8 = *(const short8*)&pj[(size_t)(Rbase + row) * STRIDE + n * 64 + sub * 8];
            #pragma unroll
            for (int j = 0; j < 8; ++j) Pt[(sub * 8 + j) * 72 + row] = p8[j];
        }
        __syncthreads();
        // ---- qm for all 128 rows (2 strips of 16 per wave) ----
        #pragma unroll
        for (int s = 0; s < 2; ++s) {
            int vrow = Rbase + wave * 32 + s * 16;
            const short* arow = pj + (size_t)(vrow + c) * STRIDE + n * 64;
            short8 a0 = *(const short8*)(arow + q * 8);
            short8 a1 = *(const short8*)(arow + 32 + q * 8);
            #pragma unroll
            for (int ct = 0; ct < 4; ++ct) {
                f32x4 qa = {};
                qa = MFMA(a0, mb0[ct], qa);
                qa = MFMA(a1, mb1[ct], qa);
                #pragma unroll
                for (int r = 0; r < 4; ++r)
                    pjm[(size_t)(vrow + q * 4 + r) * STRIDE + 1024 + n * 64 + ct * 16 + c] = f2bf(qa[r]);
            }
        }
        // ---- O for chunk 0 (ccA <= 30, always computed) ----
        {
            short8 a0 = *(const short8*)&Pt[(wave * 16 + c) * 72 + q * 8];
            short8 a1 = *(const short8*)&Pt[(wave * 16 + c) * 72 + 32 + q * 8];
            size_t cbase = (bnI * 32 + ccA) * 4096;
            #pragma unroll
            for (int tj = 0; tj < 4; ++tj) {
                short8 b0 = *(const short8*)&Pt[(tj * 16 + c) * 72 + q * 8];
                short8 b1 = *(const short8*)&Pt[(tj * 16 + c) * 72 + 32 + q * 8];
                f32x4 oa = {};
                oa = MFMA(a0, b0, oa);
                oa = MFMA(a1, b1, oa);
                s16x4 hi, lo;
                #pragma unroll
                for (int r = 0; r < 4; ++r) {
                    float a = oa[r];
                    short hh = f2bf(a);
                    hi[r] = hh;
                    lo[r] = f2bf(a - bf2f(hh));
                }
                size_t off2 = cbase + (size_t)(tj * 16 + c) * 64 + wave * 16 + q * 4;
                *(s16x4*)&Chi[off2] = hi;
                *(s16x4*)&Clo[off2] = lo;
            }
        }
        __syncthreads();
        // ---- stage Pt for chunk 1 ----
        #pragma unroll
        for (int e = 0; e < 2; ++e) {
            int chv = e * 256 + t, row = chv >> 3, sub = chv & 7;
            short8 p8 = *(const short8*)&pj[(size_t)(Rbase + 64 + row) * STRIDE + n * 64 + sub * 8];
            #pragma unroll
            for (int j = 0; j < 8; ++j) Pt[(sub * 8 + j) * 72 + row] = p8[j];
        }
        __syncthreads();
        // ---- O for chunk 1 (skip cc==31: its O is never consumed) ----
        if (ccA + 1 < 31) {
            short8 a0 = *(const short8*)&Pt[(wave * 16 + c) * 72 + q * 8];
            short8 a1 = *(const short8*)&Pt[(wave * 16 + c) * 72 + 32 + q * 8];
            size_t cbase = (bnI * 32 + ccA + 1) * 4096;
            #pragma unroll
            for (int tj = 0; tj < 4; ++tj) {
                short8 b0 = *(const short8*)&Pt[(tj * 16 + c) * 72 + q * 8];
                short8 b1 = *(const short8*)&Pt[(tj * 16 + c) * 72 + 32 + q * 8];
                f32x4 oa = {};
                oa = MFMA(a0, b0, oa);
                oa = MFMA(a1, b1, oa);
                s16x4 hi, lo;
                #pragma unroll
                for (int r = 0; r < 4; ++r) {
                    float a = oa[r];
                    short hh = f2bf(a);
                    hi[r] = hh;
                    lo[r] = f2bf(a - bf2f(hh));
                }
                size_t off2 = cbase + (size_t)(tj * 16 + c) * 64 + wave * 16 + q * 4;
                *(s16x4*)&Chi[off2] = hi;
                *(s16x4*)&Clo[off2] = lo;
            }
        }
    }
}

// ---------------- k_scan: in-place exclusive prefix over the 32 chunk slots ----------------
// ROUND-10: 2-deep prefetch (4 outstanding loads/thread) — 1-deep left only ~4KB/CU in
// flight at 1 block/CU -> latency-bound. Store(cc) never aliases load(cc+2).
__global__ __launch_bounds__(256) void k_scan(short* __restrict__ Chi, short* __restrict__ Clo) {
    int bn = blockIdx.y;
    int el = blockIdx.x * 1024 + threadIdx.x * 4;
    size_t off = (size_t)bn * 32 * 4096 + el;
    float run[4] = {0.f, 0.f, 0.f, 0.f};
    s16x4 h0 = *(const s16x4*)&Chi[off];
    s16x4 l0 = *(const s16x4*)&Clo[off];
    s16x4 h1 = *(const s16x4*)&Chi[off + 4096];
    s16x4 l1 = *(const s16x4*)&Clo[off + 4096];
    for (int cc = 0; cc < 31; ++cc) {
        s16x4 nh, nl;
        if (cc < 29) {
            nh = *(const s16x4*)&Chi[off + 8192];
            nl = *(const s16x4*)&Clo[off + 8192];
        }
        s16x4 oh, ol;
        #pragma unroll
        for (int r = 0; r < 4; ++r) {
            float o = bf2f(h0[r]) + bf2f(l0[r]);
            float cv = run[r];
            short hh = f2bf(cv);
            oh[r] = hh;
            ol[r] = f2bf(cv - bf2f(hh));
            run[r] = cv + o;
        }
        *(s16x4*)&Chi[off] = oh;
        *(s16x4*)&Clo[off] = ol;
        h0 = h1; l0 = l1; h1 = nh; l1 = nl;
        off += 4096;
    }
    s16x4 oh, ol;
    #pragma unroll
    for (int r = 0; r < 4; ++r) {
        short hh = f2bf(run[r]);
        oh[r] = hh;
        ol[r] = f2bf(run[r] - bf2f(hh));
    }
    *(s16x4*)&Chi[off] = oh;
    *(s16x4*)&Clo[off] = ol;
}

// ---------------- k_chunk: nudged_c = causal_intra(QM_c,P_c) + QM_c @ (Chi+Clo) ----------------
__global__ __launch_bounds__(256) void k_chunk(const short* __restrict__ pjqm,
                                               const short* __restrict__ Chi, const short* __restrict__ Clo,
                                               short* __restrict__ Nd) {
    int cc = blockIdx.x, n = blockIdx.y, b = blockIdx.z;
    int t = threadIdx.x, wave = t >> 6, lane = t & 63;
    int q = lane >> 4, c = lane & 15;
    __shared__ short Ps[64 * 72];     // P_c   [v][k]
    __shared__ short Pt_s[64 * 72];   // P_c^T [k][v]
    __shared__ short Ch[64 * 72];     // C_hi  [j][k]
    __shared__ short Cl[64 * 72];     // C_lo  [j][k]
    __shared__ short St[4][16 * 72];  // per-wave S strip [w][v]
    int w0g = b * W_ + cc * 64;

    const short* qmrow = &pjqm[(size_t)(w0g + wave * 16 + c) * 2048 + 1024 + n * KH];
    short8 bq0 = *(const short8*)(qmrow + q * 8);
    short8 bq1 = *(const short8*)(qmrow + 32 + q * 8);

    #pragma unroll
    for (int e = 0; e < 2; ++e) {
        int chv = e * 256 + t, row = chv >> 3, sub = chv & 7;
        short8 p8 = *(const short8*)&pjqm[(size_t)(w0g + row) * 2048 + n * KH + sub * 8];
        *(short8*)&Ps[row * 72 + sub * 8] = p8;
        #pragma unroll
        for (int j = 0; j < 8; ++j) Pt_s[(sub * 8 + j) * 72 + row] = p8[j];
        size_t cbase = ((size_t)((b * NH + n) * 32 + cc)) * 4096;
        *(short8*)&Ch[row * 72 + sub * 8] = *(const short8*)&Chi[cbase + row * 64 + sub * 8];
        *(short8*)&Cl[row * 72 + sub * 8] = *(const short8*)&Clo[cbase + row * 64 + sub * 8];
    }
    __syncthreads();
    #pragma unroll
    for (int ct = 0; ct < 4; ++ct) {
        short8 a0 = *(const short8*)&Ps[(ct * 16 + c) * 72 + q * 8];
        short8 a1 = *(const short8*)&Ps[(ct * 16 + c) * 72 + 32 + q * 8];
        f32x4 s = {};
        s = MFMA(a0, bq0, s);
        s = MFMA(a1, bq1, s);
        int vb = ct * 16 + q * 4, wl = wave * 16 + c;
        s16x4 pk;
        #pragma unroll
        for (int r = 0; r < 4; ++r) {
            float v = s[r];
            if (vb + r > wl) v = 0.f;
            pk[r] = f2bf(v);
        }
        *(s16x4*)&St[wave][c * 72 + ct * 16 + q * 4] = pk;
    }
    __syncthreads();
    f32x4 oc[4] = {};
    short8 as0 = *(const short8*)&St[wave][c * 72 + q * 8];
    short8 as1 = *(const short8*)&St[wave][c * 72 + 32 + q * 8];
    #pragma unroll
    for (int tj = 0; tj < 4; ++tj) {
        short8 bp0 = *(const short8*)&Pt_s[(tj * 16 + c) * 72 + q * 8];
        short8 bp1 = *(const short8*)&Pt_s[(tj * 16 + c) * 72 + 32 + q * 8];
        oc[tj] = MFMA(as0, bp0, oc[tj]);
        oc[tj] = MFMA(as1, bp1, oc[tj]);
        short8 bh0 = *(const short8*)&Ch[(tj * 16 + c) * 72 + q * 8];
        short8 bh1 = *(const short8*)&Ch[(tj * 16 + c) * 72 + 32 + q * 8];
        oc[tj] = MFMA(bq0, bh0, oc[tj]);
        oc[tj] = MFMA(bq1, bh1, oc[tj]);
        short8 bl0 = *(const short8*)&Cl[(tj * 16 + c) * 72 + q * 8];
        short8 bl1 = *(const short8*)&Cl[(tj * 16 + c) * 72 + 32 + q * 8];
        oc[tj] = MFMA(bq0, bl0, oc[tj]);
        oc[tj] = MFMA(bq1, bl1, oc[tj]);
    }
    #pragma unroll
    for (int tj = 0; tj < 4; ++tj)
        #pragma unroll
        for (int r = 0; r < 4; ++r)
            Nd[(size_t)(w0g + wave * 16 + q * 4 + r) * C_ + n * KH + tj * 16 + c] = f2bf(oc[tj][r]);
}

extern "C" void kernel_launch(void* const* d_in, const int* in_sizes, int n_in,
                              void* d_out, int out_size, void* d_ws, size_t ws_size,
                              hipStream_t stream) {
    const float* x  = (const float*)d_in[0];
    const float* Wp = (const float*)d_in[1];
    const float* Pm = (const float*)d_in[2];
    const float* Tr = (const float*)d_in[3];
    const float* Wm = (const float*)d_in[4];
    float* out = (float*)d_out;
    char* ws = (char*)d_ws;

    const size_t MB = 1024 * 1024;
    float* metric = (float*)ws;                        // 256 KB (fp32, consumed by GEMM1 epilogue)
    short* wp16  = (short*)(ws + 256 * 1024);          // 2 MB
    short* wf16  = (short*)(ws + 256 * 1024 + 4 * MB); // 2 MB
    short* x16   = (short*)(ws + 256 * 1024 + 6 * MB); // 16 MB (aliased by nd16 later)
    short* pjqm  = (short*)(ws + 256 * 1024 + 22 * MB);// 32 MB: [8192][2048] = [proj | qm]
    short* nd16  = x16;                                // x16 dead after GEMM1
    short* Chi   = (short*)d_out;                      // d_out as scratch: 16.75 MB
    short* Clo   = Chi + 8 * MB;                       // 16.75 MB (exactly fills d_out)

    k_prep<<<dim3(1424), dim3(256), 0, stream>>>(x, Wp, Pm, Tr, Wm, x16, wp16, wf16, metric);
    // proj into pjqm left half + fused {qm, O outer-products} epilogue
    k_gemm<1024, 2048, false, true><<<dim3(16, 64), dim3(256), 0, stream>>>(
        x16, wp16, (void*)pjqm, metric, Chi, Clo);
    k_scan<<<dim3(4, 64), dim3(256), 0, stream>>>(Chi, Clo);
    k_chunk<<<dim3(32, NH, B_), dim3(256), 0, stream>>>(pjqm, Chi, Clo, nd16);
    k_gemm<1024, 1024, true, false><<<dim3(16, 64), dim3(256), 0, stream>>>(
        nd16, wf16, (void*)out, nullptr, nullptr, nullptr);
}

// Round 11
// 200.257 us; speedup vs baseline: 1.0492x; 1.0492x over previous
//
#include <hip/hip_runtime.h>

#define B_ 4
#define W_ 2048
#define C_ 1024
#define NH 16
#define KH 64

typedef __attribute__((ext_vector_type(8))) short short8;
typedef __attribute__((ext_vector_type(4))) short s16x4;
typedef __attribute__((ext_vector_type(4))) float f32x4;

__device__ __forceinline__ short f2bf(float f) {
    unsigned u = __builtin_bit_cast(unsigned, f);
    u = (u + 0x7FFFu + ((u >> 16) & 1u)) >> 16;
    return (short)u;
}
__device__ __forceinline__ float bf2f(short h) {
    return __builtin_bit_cast(float, ((unsigned)(unsigned short)h) << 16);
}

#define MFMA(a, b, cc) __builtin_amdgcn_mfma_f32_16x16x32_bf16(a, b, cc, 0, 0, 0)

// ---------------- k_prep: fused {cvt x, cvt Wp, Wf build, metric} ----------------
//   [0,1024)    : x fp32 -> bf16   (2048 float4/block, 8/thread)
//   [1024,1152) : Wp fp32 -> bf16  (2048 float4/block, 8/thread)
//   [1152,1408) : Wf[o][n*64+k] = sum_j T[n][k][j] * Wm[o][n*64+j]
//   [1408,1424) : metric[n] = P[n] @ P[n]^T  (fp32, consumed by k_outer)
__global__ __launch_bounds__(256) void k_prep(const float* __restrict__ x, const float* __restrict__ Wp,
                                              const float* __restrict__ Pm, const float* __restrict__ Tr,
                                              const float* __restrict__ Wm,
                                              short* __restrict__ x16, short* __restrict__ wp16,
                                              short* __restrict__ wf16, float* __restrict__ metric) {
    int bid = blockIdx.x, t = threadIdx.x;
    __shared__ float sA[KH * 65];
    __shared__ float sB[KH * KH];
    if (bid < 1152) {
        const float4* src;
        short4* dst;
        int base;
        if (bid < 1024) { src = (const float4*)x;  dst = (short4*)x16;  base = bid * 2048 + t; }
        else            { src = (const float4*)Wp; dst = (short4*)wp16; base = (bid - 1024) * 2048 + t; }
        float4 v[8];
        #pragma unroll
        for (int e = 0; e < 8; ++e) v[e] = src[base + e * 256];
        #pragma unroll
        for (int e = 0; e < 8; ++e) {
            short4 o;
            o.x = f2bf(v[e].x); o.y = f2bf(v[e].y); o.z = f2bf(v[e].z); o.w = f2bf(v[e].w);
            dst[base + e * 256] = o;
        }
    } else if (bid < 1408) {
        int idx = bid - 1152;
        int oseg = idx & 15, n = idx >> 4;
        for (int i = t; i < KH * KH; i += 256) {
            sA[(i & 63) * 65 + (i >> 6)] = Tr[n * KH * KH + i];   // T^T
            int r = i >> 6, c = i & 63;
            sB[i] = Wm[(oseg * KH + r) * C_ + n * KH + c];
        }
        __syncthreads();
        for (int e = t; e < KH * KH; e += 256) {
            int r = e >> 6, k = e & 63;
            float s = 0.f;
            #pragma unroll 8
            for (int j = 0; j < KH; ++j) s += sA[j * 65 + k] * sB[r * KH + j];
            wf16[(oseg * KH + r) * C_ + n * KH + k] = f2bf(s);
        }
    } else {
        int n = bid - 1408;
        const float* Pn = Pm + n * KH * KH;
        for (int i = t; i < KH * KH; i += 256) {
            float v = Pn[i];
            sB[i] = v;
            sA[(i & 63) * 65 + (i >> 6)] = v;                      // P^T
        }
        __syncthreads();
        float* Mn = metric + n * KH * KH;
        for (int e = t; e < KH * KH; e += 256) {
            int i = e >> 6, k = e & 63;
            float s = 0.f;
            #pragma unroll 8
            for (int j = 0; j < KH; ++j) s += sB[i * KH + j] * sA[j * 65 + k];
            Mn[e] = s;
        }
    }
}

// ---------------- 128x64-tile m97-style GEMM: Out[M][col] = A[M][1024] @ Bw[col][1024]^T --------
// BN=64 -> grid (OC/64, 64) = 1024 blocks = 4 blocks/CU. STRIDE = Out row stride.
// ROUND-11: fusion of outer/qm into the epilogue REVERTED (round-10: 60us fused vs ~37us
// separate — epilogue transpose-scatter (2.15M bank conflicts) + global re-read serialized
// on every block's tail with no cross-block overlap).
template <int OC, int STRIDE, bool OUT_FP32>
__global__ __launch_bounds__(256) void k_gemm(const short* __restrict__ A, const short* __restrict__ Bw,
                                              void* __restrict__ Out) {
    __shared__ short As[128 * 64];
    __shared__ short Bs[64 * 64];
    constexpr int NBX = OC / 64;
    int id = blockIdx.x + blockIdx.y * NBX;
    int fl = (id & 7) * (NBX * 64 / 8) + (id >> 3);   // bijective XCD swizzle (grid %8==0)
    int bm = fl / NBX, bn = fl % NBX;
    int t = threadIdx.x;
    int wave = t >> 6, lane = t & 63;
    int q = lane >> 4, c = lane & 15;
    int wy = wave >> 1, wx = wave & 1;                 // wave tile: 64 rows x 32 cols
    f32x4 acc[4][2] = {};
    int xsw = (c & 7);
    for (int k0 = 0; k0 < C_; k0 += 64) {
        __syncthreads();
        #pragma unroll
        for (int e = 0; e < 4; ++e) {
            int row = (e * 256 + t) >> 3;
            int ks = ((t & 7) ^ (row & 7)) * 8;
            __builtin_amdgcn_global_load_lds(
                (const __attribute__((address_space(1))) void*)&A[(size_t)(bm * 128 + row) * C_ + k0 + ks],
                (__attribute__((address_space(3))) void*)&As[e * 2048 + wave * 512], 16, 0, 0);
        }
        #pragma unroll
        for (int e = 0; e < 2; ++e) {
            int row = (e * 256 + t) >> 3;
            int ks = ((t & 7) ^ (row & 7)) * 8;
            __builtin_amdgcn_global_load_lds(
                (const __attribute__((address_space(1))) void*)&Bw[(size_t)(bn * 64 + row) * C_ + k0 + ks],
                (__attribute__((address_space(3))) void*)&Bs[e * 2048 + wave * 512], 16, 0, 0);
        }
        __syncthreads();
        #pragma unroll
        for (int kk = 0; kk < 64; kk += 32) {
            int o = kk >> 3;
            int xo = ((o + q) ^ xsw) * 8;
            short8 af[4], bfr[2];
            #pragma unroll
            for (int i = 0; i < 4; ++i)
                af[i] = *(const short8*)&As[(wy * 64 + i * 16 + c) * 64 + xo];
            #pragma unroll
            for (int j = 0; j < 2; ++j)
                bfr[j] = *(const short8*)&Bs[(wx * 32 + j * 16 + c) * 64 + xo];
            #pragma unroll
            for (int i = 0; i < 4; ++i)
                #pragma unroll
                for (int j = 0; j < 2; ++j)
                    acc[i][j] = MFMA(af[i], bfr[j], acc[i][j]);
        }
    }
    #pragma unroll
    for (int i = 0; i < 4; ++i)
        #pragma unroll
        for (int j = 0; j < 2; ++j)
            #pragma unroll
            for (int r = 0; r < 4; ++r) {
                int row = bm * 128 + wy * 64 + i * 16 + q * 4 + r;
                int col = bn * 64 + wx * 32 + j * 16 + c;
                if (OUT_FP32) ((float*)Out)[(size_t)row * STRIDE + col] = acc[i][j][r];
                else ((short*)Out)[(size_t)row * STRIDE + col] = f2bf(acc[i][j][r]);
            }
}

// ---------------- k_outer (fused qm): per (b,n,cc 64-row chunk) ----------------
// Always: qm[w][n*64+j] = sum_k proj[w][n*64+k] * (0.125*M_n)[j][k]  (K=64 MFMA, 8/wave)
// cc<31 : O_cc = P_cc^T @ P_cc -> bf16 hi/lo into Chi/Clo slot        (8 MFMA/wave)
__global__ __launch_bounds__(256) void k_outer(short* __restrict__ pjqm,
                                               const float* __restrict__ metric,
                                               short* __restrict__ Chi, short* __restrict__ Clo) {
    int cc = blockIdx.x, n = blockIdx.y, b = blockIdx.z;
    int bn = b * NH + n;
    int t = threadIdx.x, wave = t >> 6, lane = t & 63;
    int q = lane >> 4, c = lane & 15;
    int w0g = b * W_ + cc * 64;
    __shared__ short Pt_s[64 * 72];   // P_cc^T [k][v]
    __shared__ short Mb[64 * 72];     // 0.125 * M_n, [j][k]

    const float* Mn = metric + n * 4096;
    #pragma unroll
    for (int e = 0; e < 4; ++e) {
        int i4 = e * 256 + t;
        float4 v = ((const float4*)Mn)[i4];
        s16x4 o;
        o[0] = f2bf(v.x * 0.125f); o[1] = f2bf(v.y * 0.125f);
        o[2] = f2bf(v.z * 0.125f); o[3] = f2bf(v.w * 0.125f);
        int row = i4 >> 4, col = (i4 & 15) * 4;
        *(s16x4*)&Mb[row * 72 + col] = o;
    }
    if (cc < 31) {
        #pragma unroll
        for (int e = 0; e < 2; ++e) {
            int chv = e * 256 + t, row = chv >> 3, sub = chv & 7;
            short8 p8 = *(const short8*)&pjqm[(size_t)(w0g + row) * 2048 + n * KH + sub * 8];
            #pragma unroll
            for (int j = 0; j < 8; ++j) Pt_s[(sub * 8 + j) * 72 + row] = p8[j];
        }
    }
    __syncthreads();

    // qm: each wave handles its 16 rows (A-frags straight from global, L2-hot)
    {
        const short* arow = &pjqm[(size_t)(w0g + wave * 16 + c) * 2048 + n * KH];
        short8 a0 = *(const short8*)(arow + q * 8);
        short8 a1 = *(const short8*)(arow + 32 + q * 8);
        #pragma unroll
        for (int ct = 0; ct < 4; ++ct) {
            short8 b0 = *(const short8*)&Mb[(ct * 16 + c) * 72 + q * 8];
            short8 b1 = *(const short8*)&Mb[(ct * 16 + c) * 72 + 32 + q * 8];
            f32x4 acc = {};
            acc = MFMA(a0, b0, acc);
            acc = MFMA(a1, b1, acc);
            #pragma unroll
            for (int r = 0; r < 4; ++r)
                pjqm[(size_t)(w0g + wave * 16 + q * 4 + r) * 2048 + 1024 + n * KH + ct * 16 + c] =
                    f2bf(acc[r]);
        }
    }

    if (cc < 31) {
        short8 a0 = *(const short8*)&Pt_s[(wave * 16 + c) * 72 + q * 8];
        short8 a1 = *(const short8*)&Pt_s[(wave * 16 + c) * 72 + 32 + q * 8];
        size_t cbase = ((size_t)bn * 32 + cc) * 4096;
        #pragma unroll
        for (int tj = 0; tj < 4; ++tj) {
            short8 b0 = *(const short8*)&Pt_s[(tj * 16 + c) * 72 + q * 8];
            short8 b1 = *(const short8*)&Pt_s[(tj * 16 + c) * 72 + 32 + q * 8];
            f32x4 acc = {};
            acc = MFMA(a0, b0, acc);
            acc = MFMA(a1, b1, acc);
            s16x4 hi, lo;
            #pragma unroll
            for (int r = 0; r < 4; ++r) {
                float a = acc[r];
                short h = f2bf(a);
                hi[r] = h;
                lo[r] = f2bf(a - bf2f(h));
            }
            size_t off = cbase + (size_t)(tj * 16 + c) * 64 + wave * 16 + q * 4;  // [j][k], sym
            *(s16x4*)&Chi[off] = hi;
            *(s16x4*)&Clo[off] = lo;
        }
    }
}

// ---------------- k_scan: in-place exclusive prefix over the 32 chunk slots ----------------
// 2-deep prefetch (4 outstanding loads/thread); store(cc) never aliases load(cc+2).
__global__ __launch_bounds__(256) void k_scan(short* __restrict__ Chi, short* __restrict__ Clo) {
    int bn = blockIdx.y;
    int el = blockIdx.x * 1024 + threadIdx.x * 4;
    size_t off = (size_t)bn * 32 * 4096 + el;
    float run[4] = {0.f, 0.f, 0.f, 0.f};
    s16x4 h0 = *(const s16x4*)&Chi[off];
    s16x4 l0 = *(const s16x4*)&Clo[off];
    s16x4 h1 = *(const s16x4*)&Chi[off + 4096];
    s16x4 l1 = *(const s16x4*)&Clo[off + 4096];
    for (int cc = 0; cc < 31; ++cc) {
        s16x4 nh, nl;
        if (cc < 29) {
            nh = *(const s16x4*)&Chi[off + 8192];
            nl = *(const s16x4*)&Clo[off + 8192];
        }
        s16x4 oh, ol;
        #pragma unroll
        for (int r = 0; r < 4; ++r) {
            float o = bf2f(h0[r]) + bf2f(l0[r]);
            float cv = run[r];
            short hh = f2bf(cv);
            oh[r] = hh;
            ol[r] = f2bf(cv - bf2f(hh));
            run[r] = cv + o;
        }
        *(s16x4*)&Chi[off] = oh;
        *(s16x4*)&Clo[off] = ol;
        h0 = h1; l0 = l1; h1 = nh; l1 = nl;
        off += 4096;
    }
    s16x4 oh, ol;
    #pragma unroll
    for (int r = 0; r < 4; ++r) {
        short hh = f2bf(run[r]);
        oh[r] = hh;
        ol[r] = f2bf(run[r] - bf2f(hh));
    }
    *(s16x4*)&Chi[off] = oh;
    *(s16x4*)&Clo[off] = ol;
}

// ---------------- k_chunk: nudged_c = causal_intra(QM_c,P_c) + QM_c @ (Chi+Clo) ----------------
__global__ __launch_bounds__(256) void k_chunk(const short* __restrict__ pjqm,
                                               const short* __restrict__ Chi, const short* __restrict__ Clo,
                                               short* __restrict__ Nd) {
    int cc = blockIdx.x, n = blockIdx.y, b = blockIdx.z;
    int t = threadIdx.x, wave = t >> 6, lane = t & 63;
    int q = lane >> 4, c = lane & 15;
    __shared__ short Ps[64 * 72];     // P_c   [v][k]
    __shared__ short Pt_s[64 * 72];   // P_c^T [k][v]
    __shared__ short Ch[64 * 72];     // C_hi  [j][k]
    __shared__ short Cl[64 * 72];     // C_lo  [j][k]
    __shared__ short St[4][16 * 72];  // per-wave S strip [w][v]
    int w0g = b * W_ + cc * 64;

    const short* qmrow = &pjqm[(size_t)(w0g + wave * 16 + c) * 2048 + 1024 + n * KH];
    short8 bq0 = *(const short8*)(qmrow + q * 8);
    short8 bq1 = *(const short8*)(qmrow + 32 + q * 8);

    #pragma unroll
    for (int e = 0; e < 2; ++e) {
        int chv = e * 256 + t, row = chv >> 3, sub = chv & 7;
        short8 p8 = *(const short8*)&pjqm[(size_t)(w0g + row) * 2048 + n * KH + sub * 8];
        *(short8*)&Ps[row * 72 + sub * 8] = p8;
        #pragma unroll
        for (int j = 0; j < 8; ++j) Pt_s[(sub * 8 + j) * 72 + row] = p8[j];
        size_t cbase = ((size_t)((b * NH + n) * 32 + cc)) * 4096;
        *(short8*)&Ch[row * 72 + sub * 8] = *(const short8*)&Chi[cbase + row * 64 + sub * 8];
        *(short8*)&Cl[row * 72 + sub * 8] = *(const short8*)&Clo[cbase + row * 64 + sub * 8];
    }
    __syncthreads();
    #pragma unroll
    for (int ct = 0; ct < 4; ++ct) {
        short8 a0 = *(const short8*)&Ps[(ct * 16 + c) * 72 + q * 8];
        short8 a1 = *(const short8*)&Ps[(ct * 16 + c) * 72 + 32 + q * 8];
        f32x4 s = {};
        s = MFMA(a0, bq0, s);
        s = MFMA(a1, bq1, s);
        int vb = ct * 16 + q * 4, wl = wave * 16 + c;
        s16x4 pk;
        #pragma unroll
        for (int r = 0; r < 4; ++r) {
            float v = s[r];
            if (vb + r > wl) v = 0.f;
            pk[r] = f2bf(v);
        }
        *(s16x4*)&St[wave][c * 72 + ct * 16 + q * 4] = pk;
    }
    __syncthreads();
    f32x4 oc[4] = {};
    short8 as0 = *(const short8*)&St[wave][c * 72 + q * 8];
    short8 as1 = *(const short8*)&St[wave][c * 72 + 32 + q * 8];
    #pragma unroll
    for (int tj = 0; tj < 4; ++tj) {
        short8 bp0 = *(const short8*)&Pt_s[(tj * 16 + c) * 72 + q * 8];
        short8 bp1 = *(const short8*)&Pt_s[(tj * 16 + c) * 72 + 32 + q * 8];
        oc[tj] = MFMA(as0, bp0, oc[tj]);
        oc[tj] = MFMA(as1, bp1, oc[tj]);
        short8 bh0 = *(const short8*)&Ch[(tj * 16 + c) * 72 + q * 8];
        short8 bh1 = *(const short8*)&Ch[(tj * 16 + c) * 72 + 32 + q * 8];
        oc[tj] = MFMA(bq0, bh0, oc[tj]);
        oc[tj] = MFMA(bq1, bh1, oc[tj]);
        short8 bl0 = *(const short8*)&Cl[(tj * 16 + c) * 72 + q * 8];
        short8 bl1 = *(const short8*)&Cl[(tj * 16 + c) * 72 + 32 + q * 8];
        oc[tj] = MFMA(bq0, bl0, oc[tj]);
        oc[tj] = MFMA(bq1, bl1, oc[tj]);
    }
    #pragma unroll
    for (int tj = 0; tj < 4; ++tj)
        #pragma unroll
        for (int r = 0; r < 4; ++r)
            Nd[(size_t)(w0g + wave * 16 + q * 4 + r) * C_ + n * KH + tj * 16 + c] = f2bf(oc[tj][r]);
}

extern "C" void kernel_launch(void* const* d_in, const int* in_sizes, int n_in,
                              void* d_out, int out_size, void* d_ws, size_t ws_size,
                              hipStream_t stream) {
    const float* x  = (const float*)d_in[0];
    const float* Wp = (const float*)d_in[1];
    const float* Pm = (const float*)d_in[2];
    const float* Tr = (const float*)d_in[3];
    const float* Wm = (const float*)d_in[4];
    float* out = (float*)d_out;
    char* ws = (char*)d_ws;

    const size_t MB = 1024 * 1024;
    float* metric = (float*)ws;                        // 256 KB (fp32, consumed by k_outer)
    short* wp16  = (short*)(ws + 256 * 1024);          // 2 MB
    short* wf16  = (short*)(ws + 256 * 1024 + 4 * MB); // 2 MB
    short* x16   = (short*)(ws + 256 * 1024 + 6 * MB); // 16 MB (aliased by nd16 later)
    short* pjqm  = (short*)(ws + 256 * 1024 + 22 * MB);// 32 MB: [8192][2048] = [proj | qm]
    short* nd16  = x16;                                // x16 dead after GEMM1
    short* Chi   = (short*)d_out;                      // d_out as scratch: 16.75 MB
    short* Clo   = Chi + 8 * MB;                       // 16.75 MB (exactly fills d_out)

    k_prep<<<dim3(1424), dim3(256), 0, stream>>>(x, Wp, Pm, Tr, Wm, x16, wp16, wf16, metric);
    // proj into pjqm left half (OC=1024, row stride 2048)
    k_gemm<1024, 2048, false><<<dim3(16, 64), dim3(256), 0, stream>>>(x16, wp16, (void*)pjqm);
    // O outer-products + fused qm (qm = proj @ M/8 into pjqm right half)
    k_outer<<<dim3(32, NH, B_), dim3(256), 0, stream>>>(pjqm, metric, Chi, Clo);
    k_scan<<<dim3(4, 64), dim3(256), 0, stream>>>(Chi, Clo);
    k_chunk<<<dim3(32, NH, B_), dim3(256), 0, stream>>>(pjqm, Chi, Clo, nd16);
    k_gemm<1024, 1024, true><<<dim3(16, 64), dim3(256), 0, stream>>>(nd16, wf16, (void*)out);
}

// Round 12
// 196.408 us; speedup vs baseline: 1.0698x; 1.0196x over previous
//
#include <hip/hip_runtime.h>

#define B_ 4
#define W_ 2048
#define C_ 1024
#define NH 16
#define KH 64

typedef __attribute__((ext_vector_type(8))) short short8;
typedef __attribute__((ext_vector_type(4))) short s16x4;
typedef __attribute__((ext_vector_type(4))) float f32x4;

__device__ __forceinline__ short f2bf(float f) {
    unsigned u = __builtin_bit_cast(unsigned, f);
    u = (u + 0x7FFFu + ((u >> 16) & 1u)) >> 16;
    return (short)u;
}
__device__ __forceinline__ float bf2f(short h) {
    return __builtin_bit_cast(float, ((unsigned)(unsigned short)h) << 16);
}

// Skewed transposed-P layout: PT(k,v) = k*72 + (k>>3)*8 + v.
// Write side (scatter Pt[PT(s*8+j, row)]): addr = s*584 + j*72 + row; 584>>1 = 292 = 4 mod 32
// -> bank = 4*s + (row>>1) + const: bijective over 32 banks (vs old 72-stride: 288 = 0 mod 32,
// 16-way conflict -> the 2.15M SQ_LDS_BANK_CONFLICT signature). Read side stays b128-vector,
// skew separates the c/c+8 bank collision. Same data order -> bit-identical results.
__device__ __forceinline__ int PT(int k, int v) { return k * 72 + ((k >> 3) << 3) + v; }

#define MFMA(a, b, cc) __builtin_amdgcn_mfma_f32_16x16x32_bf16(a, b, cc, 0, 0, 0)

// ---------------- k_prep: fused {cvt x, cvt Wp, Wf build, metric} ----------------
//   [0,1024)    : x fp32 -> bf16   (2048 float4/block, 8/thread)
//   [1024,1152) : Wp fp32 -> bf16  (2048 float4/block, 8/thread)
//   [1152,1408) : Wf[o][n*64+k] = sum_j T[n][k][j] * Wm[o][n*64+j]
//   [1408,1424) : metric[n] = P[n] @ P[n]^T  (fp32, consumed by k_outer)
__global__ __launch_bounds__(256) void k_prep(const float* __restrict__ x, const float* __restrict__ Wp,
                                              const float* __restrict__ Pm, const float* __restrict__ Tr,
                                              const float* __restrict__ Wm,
                                              short* __restrict__ x16, short* __restrict__ wp16,
                                              short* __restrict__ wf16, float* __restrict__ metric) {
    int bid = blockIdx.x, t = threadIdx.x;
    __shared__ float sA[KH * 65];
    __shared__ float sB[KH * KH];
    if (bid < 1152) {
        const float4* src;
        short4* dst;
        int base;
        if (bid < 1024) { src = (const float4*)x;  dst = (short4*)x16;  base = bid * 2048 + t; }
        else            { src = (const float4*)Wp; dst = (short4*)wp16; base = (bid - 1024) * 2048 + t; }
        float4 v[8];
        #pragma unroll
        for (int e = 0; e < 8; ++e) v[e] = src[base + e * 256];
        #pragma unroll
        for (int e = 0; e < 8; ++e) {
            short4 o;
            o.x = f2bf(v[e].x); o.y = f2bf(v[e].y); o.z = f2bf(v[e].z); o.w = f2bf(v[e].w);
            dst[base + e * 256] = o;
        }
    } else if (bid < 1408) {
        int idx = bid - 1152;
        int oseg = idx & 15, n = idx >> 4;
        for (int i = t; i < KH * KH; i += 256) {
            sA[(i & 63) * 65 + (i >> 6)] = Tr[n * KH * KH + i];   // T^T
            int r = i >> 6, c = i & 63;
            sB[i] = Wm[(oseg * KH + r) * C_ + n * KH + c];
        }
        __syncthreads();
        for (int e = t; e < KH * KH; e += 256) {
            int r = e >> 6, k = e & 63;
            float s = 0.f;
            #pragma unroll 8
            for (int j = 0; j < KH; ++j) s += sA[j * 65 + k] * sB[r * KH + j];
            wf16[(oseg * KH + r) * C_ + n * KH + k] = f2bf(s);
        }
    } else {
        int n = bid - 1408;
        const float* Pn = Pm + n * KH * KH;
        for (int i = t; i < KH * KH; i += 256) {
            float v = Pn[i];
            sB[i] = v;
            sA[(i & 63) * 65 + (i >> 6)] = v;                      // P^T
        }
        __syncthreads();
        float* Mn = metric + n * KH * KH;
        for (int e = t; e < KH * KH; e += 256) {
            int i = e >> 6, k = e & 63;
            float s = 0.f;
            #pragma unroll 8
            for (int j = 0; j < KH; ++j) s += sB[i * KH + j] * sA[j * 65 + k];
            Mn[e] = s;
        }
    }
}

// ---------------- 128x64-tile m97-style GEMM: Out[M][col] = A[M][1024] @ Bw[col][1024]^T --------
// BN=64 -> grid (OC/64, 64) = 1024 blocks = 4 blocks/CU. STRIDE = Out row stride.
template <int OC, int STRIDE, bool OUT_FP32>
__global__ __launch_bounds__(256) void k_gemm(const short* __restrict__ A, const short* __restrict__ Bw,
                                              void* __restrict__ Out) {
    __shared__ short As[128 * 64];
    __shared__ short Bs[64 * 64];
    constexpr int NBX = OC / 64;
    int id = blockIdx.x + blockIdx.y * NBX;
    int fl = (id & 7) * (NBX * 64 / 8) + (id >> 3);   // bijective XCD swizzle (grid %8==0)
    int bm = fl / NBX, bn = fl % NBX;
    int t = threadIdx.x;
    int wave = t >> 6, lane = t & 63;
    int q = lane >> 4, c = lane & 15;
    int wy = wave >> 1, wx = wave & 1;                 // wave tile: 64 rows x 32 cols
    f32x4 acc[4][2] = {};
    int xsw = (c & 7);
    for (int k0 = 0; k0 < C_; k0 += 64) {
        __syncthreads();
        #pragma unroll
        for (int e = 0; e < 4; ++e) {
            int row = (e * 256 + t) >> 3;
            int ks = ((t & 7) ^ (row & 7)) * 8;
            __builtin_amdgcn_global_load_lds(
                (const __attribute__((address_space(1))) void*)&A[(size_t)(bm * 128 + row) * C_ + k0 + ks],
                (__attribute__((address_space(3))) void*)&As[e * 2048 + wave * 512], 16, 0, 0);
        }
        #pragma unroll
        for (int e = 0; e < 2; ++e) {
            int row = (e * 256 + t) >> 3;
            int ks = ((t & 7) ^ (row & 7)) * 8;
            __builtin_amdgcn_global_load_lds(
                (const __attribute__((address_space(1))) void*)&Bw[(size_t)(bn * 64 + row) * C_ + k0 + ks],
                (__attribute__((address_space(3))) void*)&Bs[e * 2048 + wave * 512], 16, 0, 0);
        }
        __syncthreads();
        #pragma unroll
        for (int kk = 0; kk < 64; kk += 32) {
            int o = kk >> 3;
            int xo = ((o + q) ^ xsw) * 8;
            short8 af[4], bfr[2];
            #pragma unroll
            for (int i = 0; i < 4; ++i)
                af[i] = *(const short8*)&As[(wy * 64 + i * 16 + c) * 64 + xo];
            #pragma unroll
            for (int j = 0; j < 2; ++j)
                bfr[j] = *(const short8*)&Bs[(wx * 32 + j * 16 + c) * 64 + xo];
            #pragma unroll
            for (int i = 0; i < 4; ++i)
                #pragma unroll
                for (int j = 0; j < 2; ++j)
                    acc[i][j] = MFMA(af[i], bfr[j], acc[i][j]);
        }
    }
    #pragma unroll
    for (int i = 0; i < 4; ++i)
        #pragma unroll
        for (int j = 0; j < 2; ++j)
            #pragma unroll
            for (int r = 0; r < 4; ++r) {
                int row = bm * 128 + wy * 64 + i * 16 + q * 4 + r;
                int col = bn * 64 + wx * 32 + j * 16 + c;
                if (OUT_FP32) ((float*)Out)[(size_t)row * STRIDE + col] = acc[i][j][r];
                else ((short*)Out)[(size_t)row * STRIDE + col] = f2bf(acc[i][j][r]);
            }
}

// ---------------- k_outer (fused qm): per (b,n,cc 64-row chunk) ----------------
// Always: qm[w][n*64+j] = sum_k proj[w][n*64+k] * (0.125*M_n)[j][k]  (K=64 MFMA, 8/wave)
// cc<31 : O_cc = P_cc^T @ P_cc -> bf16 hi/lo into Chi/Clo slot        (8 MFMA/wave)
__global__ __launch_bounds__(256) void k_outer(short* __restrict__ pjqm,
                                               const float* __restrict__ metric,
                                               short* __restrict__ Chi, short* __restrict__ Clo) {
    int cc = blockIdx.x, n = blockIdx.y, b = blockIdx.z;
    int bn = b * NH + n;
    int t = threadIdx.x, wave = t >> 6, lane = t & 63;
    int q = lane >> 4, c = lane & 15;
    int w0g = b * W_ + cc * 64;
    __shared__ short Pt_s[64 * 72 + 64];   // P_cc^T, skewed PT() layout
    __shared__ short Mb[64 * 72];          // 0.125 * M_n, [j][k]

    const float* Mn = metric + n * 4096;
    #pragma unroll
    for (int e = 0; e < 4; ++e) {
        int i4 = e * 256 + t;
        float4 v = ((const float4*)Mn)[i4];
        s16x4 o;
        o[0] = f2bf(v.x * 0.125f); o[1] = f2bf(v.y * 0.125f);
        o[2] = f2bf(v.z * 0.125f); o[3] = f2bf(v.w * 0.125f);
        int row = i4 >> 4, col = (i4 & 15) * 4;
        *(s16x4*)&Mb[row * 72 + col] = o;
    }
    if (cc < 31) {
        #pragma unroll
        for (int e = 0; e < 2; ++e) {
            int chv = e * 256 + t, row = chv >> 3, sub = chv & 7;
            short8 p8 = *(const short8*)&pjqm[(size_t)(w0g + row) * 2048 + n * KH + sub * 8];
            #pragma unroll
            for (int j = 0; j < 8; ++j) Pt_s[PT(sub * 8 + j, row)] = p8[j];
        }
    }
    __syncthreads();

    // qm: each wave handles its 16 rows (A-frags straight from global, L2-hot)
    {
        const short* arow = &pjqm[(size_t)(w0g + wave * 16 + c) * 2048 + n * KH];
        short8 a0 = *(const short8*)(arow + q * 8);
        short8 a1 = *(const short8*)(arow + 32 + q * 8);
        #pragma unroll
        for (int ct = 0; ct < 4; ++ct) {
            short8 b0 = *(const short8*)&Mb[(ct * 16 + c) * 72 + q * 8];
            short8 b1 = *(const short8*)&Mb[(ct * 16 + c) * 72 + 32 + q * 8];
            f32x4 acc = {};
            acc = MFMA(a0, b0, acc);
            acc = MFMA(a1, b1, acc);
            #pragma unroll
            for (int r = 0; r < 4; ++r)
                pjqm[(size_t)(w0g + wave * 16 + q * 4 + r) * 2048 + 1024 + n * KH + ct * 16 + c] =
                    f2bf(acc[r]);
        }
    }

    if (cc < 31) {
        short8 a0 = *(const short8*)&Pt_s[PT(wave * 16 + c, q * 8)];
        short8 a1 = *(const short8*)&Pt_s[PT(wave * 16 + c, 32 + q * 8)];
        size_t cbase = ((size_t)bn * 32 + cc) * 4096;
        #pragma unroll
        for (int tj = 0; tj < 4; ++tj) {
            short8 b0 = *(const short8*)&Pt_s[PT(tj * 16 + c, q * 8)];
            short8 b1 = *(const short8*)&Pt_s[PT(tj * 16 + c, 32 + q * 8)];
            f32x4 acc = {};
            acc = MFMA(a0, b0, acc);
            acc = MFMA(a1, b1, acc);
            s16x4 hi, lo;
            #pragma unroll
            for (int r = 0; r < 4; ++r) {
                float a = acc[r];
                short h = f2bf(a);
                hi[r] = h;
                lo[r] = f2bf(a - bf2f(h));
            }
            size_t off = cbase + (size_t)(tj * 16 + c) * 64 + wave * 16 + q * 4;  // [j][k], sym
            *(s16x4*)&Chi[off] = hi;
            *(s16x4*)&Clo[off] = lo;
        }
    }
}

// ---------------- k_scan: in-place exclusive prefix over the 32 chunk slots ----------------
// 2-deep prefetch (4 outstanding loads/thread); store(cc) never aliases load(cc+2).
__global__ __launch_bounds__(256) void k_scan(short* __restrict__ Chi, short* __restrict__ Clo) {
    int bn = blockIdx.y;
    int el = blockIdx.x * 1024 + threadIdx.x * 4;
    size_t off = (size_t)bn * 32 * 4096 + el;
    float run[4] = {0.f, 0.f, 0.f, 0.f};
    s16x4 h0 = *(const s16x4*)&Chi[off];
    s16x4 l0 = *(const s16x4*)&Clo[off];
    s16x4 h1 = *(const s16x4*)&Chi[off + 4096];
    s16x4 l1 = *(const s16x4*)&Clo[off + 4096];
    for (int cc = 0; cc < 31; ++cc) {
        s16x4 nh, nl;
        if (cc < 29) {
            nh = *(const s16x4*)&Chi[off + 8192];
            nl = *(const s16x4*)&Clo[off + 8192];
        }
        s16x4 oh, ol;
        #pragma unroll
        for (int r = 0; r < 4; ++r) {
            float o = bf2f(h0[r]) + bf2f(l0[r]);
            float cv = run[r];
            short hh = f2bf(cv);
            oh[r] = hh;
            ol[r] = f2bf(cv - bf2f(hh));
            run[r] = cv + o;
        }
        *(s16x4*)&Chi[off] = oh;
        *(s16x4*)&Clo[off] = ol;
        h0 = h1; l0 = l1; h1 = nh; l1 = nl;
        off += 4096;
    }
    s16x4 oh, ol;
    #pragma unroll
    for (int r = 0; r < 4; ++r) {
        short hh = f2bf(run[r]);
        oh[r] = hh;
        ol[r] = f2bf(run[r] - bf2f(hh));
    }
    *(s16x4*)&Chi[off] = oh;
    *(s16x4*)&Clo[off] = ol;
}

// ---------------- k_chunk: nudged_c = causal_intra(QM_c,P_c) + QM_c @ (Chi+Clo) ----------------
__global__ __launch_bounds__(256) void k_chunk(const short* __restrict__ pjqm,
                                               const short* __restrict__ Chi, const short* __restrict__ Clo,
                                               short* __restrict__ Nd) {
    int cc = blockIdx.x, n = blockIdx.y, b = blockIdx.z;
    int t = threadIdx.x, wave = t >> 6, lane = t & 63;
    int q = lane >> 4, c = lane & 15;
    __shared__ short Ps[64 * 72];          // P_c   [v][k]
    __shared__ short Pt_s[64 * 72 + 64];   // P_c^T, skewed PT() layout
    __shared__ short Ch[64 * 72];          // C_hi  [j][k]
    __shared__ short Cl[64 * 72];          // C_lo  [j][k]
    __shared__ short St[4][16 * 72];       // per-wave S strip [w][v]
    int w0g = b * W_ + cc * 64;

    const short* qmrow = &pjqm[(size_t)(w0g + wave * 16 + c) * 2048 + 1024 + n * KH];
    short8 bq0 = *(const short8*)(qmrow + q * 8);
    short8 bq1 = *(const short8*)(qmrow + 32 + q * 8);

    #pragma unroll
    for (int e = 0; e < 2; ++e) {
        int chv = e * 256 + t, row = chv >> 3, sub = chv & 7;
        short8 p8 = *(const short8*)&pjqm[(size_t)(w0g + row) * 2048 + n * KH + sub * 8];
        *(short8*)&Ps[row * 72 + sub * 8] = p8;
        #pragma unroll
        for (int j = 0; j < 8; ++j) Pt_s[PT(sub * 8 + j, row)] = p8[j];
        size_t cbase = ((size_t)((b * NH + n) * 32 + cc)) * 4096;
        *(short8*)&Ch[row * 72 + sub * 8] = *(const short8*)&Chi[cbase + row * 64 + sub * 8];
        *(short8*)&Cl[row * 72 + sub * 8] = *(const short8*)&Clo[cbase + row * 64 + sub * 8];
    }
    __syncthreads();
    #pragma unroll
    for (int ct = 0; ct < 4; ++ct) {
        short8 a0 = *(const short8*)&Ps[(ct * 16 + c) * 72 + q * 8];
        short8 a1 = *(const short8*)&Ps[(ct * 16 + c) * 72 + 32 + q * 8];
        f32x4 s = {};
        s = MFMA(a0, bq0, s);
        s = MFMA(a1, bq1, s);
        int vb = ct * 16 + q * 4, wl = wave * 16 + c;
        s16x4 pk;
        #pragma unroll
        for (int r = 0; r < 4; ++r) {
            float v = s[r];
            if (vb + r > wl) v = 0.f;
            pk[r] = f2bf(v);
        }
        *(s16x4*)&St[wave][c * 72 + ct * 16 + q * 4] = pk;
    }
    __syncthreads();
    f32x4 oc[4] = {};
    short8 as0 = *(const short8*)&St[wave][c * 72 + q * 8];
    short8 as1 = *(const short8*)&St[wave][c * 72 + 32 + q * 8];
    #pragma unroll
    for (int tj = 0; tj < 4; ++tj) {
        short8 bp0 = *(const short8*)&Pt_s[PT(tj * 16 + c, q * 8)];
        short8 bp1 = *(const short8*)&Pt_s[PT(tj * 16 + c, 32 + q * 8)];
        oc[tj] = MFMA(as0, bp0, oc[tj]);
        oc[tj] = MFMA(as1, bp1, oc[tj]);
        short8 bh0 = *(const short8*)&Ch[(tj * 16 + c) * 72 + q * 8];
        short8 bh1 = *(const short8*)&Ch[(tj * 16 + c) * 72 + 32 + q * 8];
        oc[tj] = MFMA(bq0, bh0, oc[tj]);
        oc[tj] = MFMA(bq1, bh1, oc[tj]);
        short8 bl0 = *(const short8*)&Cl[(tj * 16 + c) * 72 + q * 8];
        short8 bl1 = *(const short8*)&Cl[(tj * 16 + c) * 72 + 32 + q * 8];
        oc[tj] = MFMA(bq0, bl0, oc[tj]);
        oc[tj] = MFMA(bq1, bl1, oc[tj]);
    }
    #pragma unroll
    for (int tj = 0; tj < 4; ++tj)
        #pragma unroll
        for (int r = 0; r < 4; ++r)
            Nd[(size_t)(w0g + wave * 16 + q * 4 + r) * C_ + n * KH + tj * 16 + c] = f2bf(oc[tj][r]);
}

extern "C" void kernel_launch(void* const* d_in, const int* in_sizes, int n_in,
                              void* d_out, int out_size, void* d_ws, size_t ws_size,
                              hipStream_t stream) {
    const float* x  = (const float*)d_in[0];
    const float* Wp = (const float*)d_in[1];
    const float* Pm = (const float*)d_in[2];
    const float* Tr = (const float*)d_in[3];
    const float* Wm = (const float*)d_in[4];
    float* out = (float*)d_out;
    char* ws = (char*)d_ws;

    const size_t MB = 1024 * 1024;
    float* metric = (float*)ws;                        // 256 KB (fp32, consumed by k_outer)
    short* wp16  = (short*)(ws + 256 * 1024);          // 2 MB
    short* wf16  = (short*)(ws + 256 * 1024 + 4 * MB); // 2 MB
    short* x16   = (short*)(ws + 256 * 1024 + 6 * MB); // 16 MB (aliased by nd16 later)
    short* pjqm  = (short*)(ws + 256 * 1024 + 22 * MB);// 32 MB: [8192][2048] = [proj | qm]
    short* nd16  = x16;                                // x16 dead after GEMM1
    short* Chi   = (short*)d_out;                      // d_out as scratch: 16.75 MB
    short* Clo   = Chi + 8 * MB;                       // 16.75 MB (exactly fills d_out)

    k_prep<<<dim3(1424), dim3(256), 0, stream>>>(x, Wp, Pm, Tr, Wm, x16, wp16, wf16, metric);
    // proj into pjqm left half (OC=1024, row stride 2048)
    k_gemm<1024, 2048, false><<<dim3(16, 64), dim3(256), 0, stream>>>(x16, wp16, (void*)pjqm);
    // O outer-products + fused qm (qm = proj @ M/8 into pjqm right half)
    k_outer<<<dim3(32, NH, B_), dim3(256), 0, stream>>>(pjqm, metric, Chi, Clo);
    k_scan<<<dim3(4, 64), dim3(256), 0, stream>>>(Chi, Clo);
    k_chunk<<<dim3(32, NH, B_), dim3(256), 0, stream>>>(pjqm, Chi, Clo, nd16);
    k_gemm<1024, 1024, true><<<dim3(16, 64), dim3(256), 0, stream>>>(nd16, wf16, (void*)out);
}